// Round 1
// baseline (150.027 us; speedup 1.0000x reference)
//
#include <hip/hip_runtime.h>

// Problem constants
#define B_    16
#define N_    1024
#define DIN_  256
#define H_    4
#define F_    64
#define COUT_ 256
#define NEG_  0.2f
#define LOG2E_ 1.4426950408889634f

typedef __bf16 bf16x8 __attribute__((ext_vector_type(8)));
typedef float  f32x4  __attribute__((ext_vector_type(4)));
typedef unsigned short u16x8 __attribute__((ext_vector_type(8)));
typedef unsigned short u16x4 __attribute__((ext_vector_type(4)));
typedef unsigned int   u32x4 __attribute__((ext_vector_type(4)));

__device__ __forceinline__ unsigned short f2bf(float f) {
    unsigned u = __builtin_bit_cast(unsigned, f);
    u += 0x7fffu + ((u >> 16) & 1u);
    return (unsigned short)(u >> 16);
}

// ---------------------------------------------------------------------------
// Prep: pack W into MFMA-B-frag order Wtp, bf16 (1KB-contiguous frag loads).
// Element (c,k): w=c>>6, ft=(c>>4)&3, l15=c&15, it=k>>5, q=(k>>3)&3, jj=k&7,
// ln=q*16+l15 -> Wtp[(((w*8+it)*4+ft)*64 + ln)*8 + jj].   [R5-proven]
// ---------------------------------------------------------------------------
__global__ __launch_bounds__(256) void prep_kernel(
    const float* __restrict__ W, unsigned short* __restrict__ Wtp) {
    const int c = blockIdx.x, k = threadIdx.x;
    const int w = c >> 6, ft = (c >> 4) & 3, l15 = c & 15;
    const int it = k >> 5, q = (k >> 3) & 3, jj = k & 7;
    const int ln = q * 16 + l15;
    Wtp[((((w * 8 + it) * 4 + ft) * 64) + ln) * 8 + jj] = f2bf(W[k * COUT_ + c]);
}

// ---------------------------------------------------------------------------
// Stage kernel.
// Part 1 (blocks 0..4095): adj -> transposed bitmask, COALESCED: one adj
//   row per wave (f32x4/lane x 4 chunks, contiguous 1KB/inst), nibble build
//   + 3x shfl_xor OR-reduce within 8-lane groups, (ln&7)==0 lanes store.
// Part 2 (blocks 4096..5119): h = x @ W via bf16 MFMA (R5 numerics) with x
//   staged through LDS (coalesced row loads, shared across all 4 waves).
//   hp frag-packed [b][h][jg][ft][ln][8] (R5 layout); e logits (x log2e)
//   from fp32 acc, stored f32 (R5 path).
// ---------------------------------------------------------------------------
__global__ __launch_bounds__(256, 4) void stage_kernel(
    const float* __restrict__ adj, const float* __restrict__ x,
    const unsigned short* __restrict__ Wtp, const float* __restrict__ a_src,
    const float* __restrict__ a_dst, unsigned int* __restrict__ mask,
    unsigned short* __restrict__ hp, float* __restrict__ e_src,
    float* __restrict__ e_dst) {
    __shared__ unsigned short xs[16][264];   // bf16 bits; padded row stride
    const int w  = threadIdx.x >> 6;
    const int ln = threadIdx.x & 63;

    if (blockIdx.x < 4096) {
        // ---- masker part: 1 row per wave, fully coalesced ----
        const int row = blockIdx.x * 4 + w;          // b*N + i, 0..16383
        const int b = row >> 10, i = row & (N_ - 1);
        const float* ar = adj + (size_t)row * N_ + ln * 4;
#pragma unroll
        for (int c = 0; c < 4; c++) {
            f32x4 v = *(const f32x4*)(ar + c * 256);
            unsigned nib = 0;
#pragma unroll
            for (int e = 0; e < 4; e++)
                nib |= (v[e] > 0.5f) ? (1u << e) : 0u;
            // lane ln covers cols c*256 + ln*4 .. +3 -> word bit (ln&7)*4+e
            unsigned word = nib << ((ln & 7) * 4);
            word |= __shfl_xor(word, 1);
            word |= __shfl_xor(word, 2);
            word |= __shfl_xor(word, 4);
            if ((ln & 7) == 0) {
                const int jc = c * 8 + (ln >> 3);
                mask[(b * 32 + jc) * N_ + i] = word;
            }
        }
    } else {
        // ---- gat_h part (bf16, R5 numerics, LDS-staged x) ----
        const int blk = blockIdx.x - 4096;
        const int b   = blk & 15;
        const int it0 = (blk >> 4) * 16;
        const int l15 = ln & 15;
        const int q   = ln >> 4;

        // Coalesced staging: wave w loads rows w*4..w*4+3 (1 row = 1KB inst),
        // converts to bf16 (RTNE), writes LDS once for all 4 waves.
#pragma unroll
        for (int s = 0; s < 4; s++) {
            const int row = w * 4 + s;
            f32x4 xv = *(const f32x4*)(x + (size_t)(b * N_ + it0 + row) * DIN_ + ln * 4);
            unsigned lo = (unsigned)f2bf(xv[0]) | ((unsigned)f2bf(xv[1]) << 16);
            unsigned hi = (unsigned)f2bf(xv[2]) | ((unsigned)f2bf(xv[3]) << 16);
            unsigned long long hb = (unsigned long long)lo | ((unsigned long long)hi << 32);
            *(unsigned long long*)&xs[row][ln * 4] = hb;
        }
        __syncthreads();

        f32x4 acc[4];
#pragma unroll
        for (int ft = 0; ft < 4; ft++) acc[ft] = (f32x4)0.0f;

        const unsigned short* wb = Wtp + (w * 8) * 4 * 64 * 8 + ln * 8;
#pragma unroll
        for (int it = 0; it < 8; it++) {
            bf16x8 af = *(const bf16x8*)&xs[l15][it * 32 + q * 8];
#pragma unroll
            for (int ft = 0; ft < 4; ft++) {
                bf16x8 bf = *((const bf16x8*)(wb + (it * 4 + ft) * 512));
                acc[ft] = __builtin_amdgcn_mfma_f32_16x16x32_bf16(af, bf, acc[ft], 0, 0, 0);
            }
        }

        // Store hp frag-packed (R5 layout). Lane holds h[i=it0+q*4+r][f=ft*16+l15].
        const int jg = it0 >> 5;
        const int q2 = 2 * ((it0 >> 4) & 1) + (q >> 1);
#pragma unroll
        for (int ft = 0; ft < 4; ft++) {
            u16x4 hb;
#pragma unroll
            for (int r = 0; r < 4; r++) hb[r] = f2bf(acc[ft][r]);
            const size_t addr =
                (size_t)((((b * H_ + w) * 32 + jg) * 4 + ft) * 64 + q2 * 16 + l15) * 8 + (q & 1) * 4;
            *((u16x4*)(hp + addr)) = hb;
        }

        // e logits from fp32 acc (x log2e), stored f32 (R5 path).
        float as_v[4], ad_v[4];
#pragma unroll
        for (int ft = 0; ft < 4; ft++) {
            as_v[ft] = a_src[w * F_ + ft * 16 + l15];
            ad_v[ft] = a_dst[w * F_ + ft * 16 + l15];
        }
        float ps[4], pd[4];
#pragma unroll
        for (int r = 0; r < 4; r++) {
            ps[r] = 0.0f; pd[r] = 0.0f;
#pragma unroll
            for (int ft = 0; ft < 4; ft++) {
                ps[r] += acc[ft][r] * as_v[ft];
                pd[r] += acc[ft][r] * ad_v[ft];
            }
        }
#pragma unroll
        for (int off = 1; off <= 8; off <<= 1)
#pragma unroll
            for (int r = 0; r < 4; r++) {
                ps[r] += __shfl_xor(ps[r], off);
                pd[r] += __shfl_xor(pd[r], off);
            }
        float vs = (l15 == 0) ? ps[0] : (l15 == 1) ? ps[1] : (l15 == 2) ? ps[2] : ps[3];
        float vd = (l15 == 0) ? pd[0] : (l15 == 1) ? pd[1] : (l15 == 2) ? pd[2] : pd[3];
        if (l15 < 4) {
            const int i = it0 + q * 4 + l15;
            e_src[(b * H_ + w) * N_ + i] = vs * LOG2E_;
            e_dst[(b * H_ + w) * N_ + i] = vd * LOG2E_;
        }
    }
}

// ---------------------------------------------------------------------------
// Kernel C: fused mask/leaky/exp2 + (P @ h) MFMA + normalize + bias.
// R5 numerics VERBATIM. R6 change: XCD-aware bijective blockIdx swizzle.
//   Each block reads hp[b] at 512 KB (16 jg x 4 frag x 4 KB x 8 waves);
//   32 blocks share each b => 268 MB of hp re-reads. Old mapping spread
//   every b across all 8 XCDs (8 MB >> 4 MB L2 => L3-served, ~10 TB/s).
//   New mapping: lid = (blockIdx&7)*64 + (blockIdx>>3) gives XCD x the
//   64 blocks with b in {2x, 2x+1} => 1 MB hp + ~0.5 MB e/mask working
//   set per XCD L2 => re-reads L2-served (~34.5 TB/s aggregate).
//   Grid 512 = 8*64 exactly => bijective (ERRATA #11 safe).
// ---------------------------------------------------------------------------
__global__ __launch_bounds__(512, 4) void gat_attn_kernel(
    const unsigned int* __restrict__ mask, const unsigned short* __restrict__ hp,
    const float* __restrict__ e_src, const float* __restrict__ e_dst,
    const float* __restrict__ bias, float* __restrict__ out) {
    const int lid = ((blockIdx.x & 7) << 6) | (blockIdx.x >> 3);  // XCD swizzle
    const int b   = lid >> 5;
    const int it0 = (lid & 31) * 32;
    const int w8  = threadIdx.x >> 6;
    const int h   = w8 & 3;             // head
    const int jh  = w8 >> 2;            // j-half
    const int ln  = threadIdx.x & 63;
    const int l15 = ln & 15;
    const int q   = ln >> 4;

    __shared__ float lds[H_][2][5][64][4];   // 40 KB: acc[2][4] + accs[2]

    float edv[2];
    edv[0] = e_dst[(b * H_ + h) * N_ + it0 + l15];
    edv[1] = e_dst[(b * H_ + h) * N_ + it0 + 16 + l15];

    const float* es_base          = e_src + (b * H_ + h) * N_;
    const unsigned short* hp_base = hp + (size_t)((b * H_ + h) * 32) * 2048 + ln * 8;
    const unsigned int* mk0       = mask + b * 32 * N_ + it0;

    f32x4 acc[2][4];
    f32x4 accs[2];
#pragma unroll
    for (int mt = 0; mt < 2; mt++) {
#pragma unroll
        for (int ft = 0; ft < 4; ft++) acc[mt][ft] = (f32x4)0.0f;
        accs[mt] = (f32x4)0.0f;
    }

    u16x8 ones_u;
#pragma unroll
    for (int jj = 0; jj < 8; jj++) ones_u[jj] = 0x3F80;   // bf16 1.0
    const bf16x8 ones = __builtin_bit_cast(bf16x8, ones_u);

    for (int jg = jh * 16; jg < jh * 16 + 16; jg++) {
        const unsigned short* hf = hp_base + jg * 2048;
        bf16x8 bfr0 = *((const bf16x8*)(hf + 0 * 512));
        bf16x8 bfr1 = *((const bf16x8*)(hf + 1 * 512));
        bf16x8 bfr2 = *((const bf16x8*)(hf + 2 * 512));
        bf16x8 bfr3 = *((const bf16x8*)(hf + 3 * 512));
        f32x4 e0 = *(const f32x4*)(es_base + jg * 32 + q * 8);
        f32x4 e1 = *(const f32x4*)(es_base + jg * 32 + q * 8 + 4);
        const unsigned m0 = mk0[jg * N_ + l15];
        const unsigned m1 = mk0[jg * N_ + 16 + l15];

        float es8[8] = {e0[0], e0[1], e0[2], e0[3], e1[0], e1[1], e1[2], e1[3]};

        bf16x8 afr[2];
#pragma unroll
        for (int mt = 0; mt < 2; mt++) {
            const unsigned mq = ((mt ? m1 : m0) >> (q * 8)) & 0xffu;
            u32x4 up;
#pragma unroll
            for (int p2 = 0; p2 < 4; p2++) {
                float t0 = edv[mt] + es8[2 * p2];
                float t1 = edv[mt] + es8[2 * p2 + 1];
                t0 = fmaxf(t0, NEG_ * t0);                 // leaky (log2-space)
                t1 = fmaxf(t1, NEG_ * t1);
                float p0 = __builtin_amdgcn_exp2f(t0);
                float p1 = __builtin_amdgcn_exp2f(t1);
                p0 = ((mq >> (2 * p2)) & 1u) ? p0 : 0.0f;
                p1 = ((mq >> (2 * p2 + 1)) & 1u) ? p1 : 0.0f;
                up[p2] = __builtin_amdgcn_perm(__builtin_bit_cast(unsigned, p1),
                                               __builtin_bit_cast(unsigned, p0),
                                               0x07060302u);
            }
            afr[mt] = __builtin_bit_cast(bf16x8, up);
        }
#pragma unroll
        for (int mt = 0; mt < 2; mt++) {
            acc[mt][0] = __builtin_amdgcn_mfma_f32_16x16x32_bf16(afr[mt], bfr0, acc[mt][0], 0, 0, 0);
            acc[mt][1] = __builtin_amdgcn_mfma_f32_16x16x32_bf16(afr[mt], bfr1, acc[mt][1], 0, 0, 0);
            acc[mt][2] = __builtin_amdgcn_mfma_f32_16x16x32_bf16(afr[mt], bfr2, acc[mt][2], 0, 0, 0);
            acc[mt][3] = __builtin_amdgcn_mfma_f32_16x16x32_bf16(afr[mt], bfr3, acc[mt][3], 0, 0, 0);
            accs[mt]   = __builtin_amdgcn_mfma_f32_16x16x32_bf16(afr[mt], ones, accs[mt], 0, 0, 0);
        }
    }

    // Cross-j-half combine via LDS.
    if (jh == 1) {
#pragma unroll
        for (int mt = 0; mt < 2; mt++) {
#pragma unroll
            for (int ft = 0; ft < 4; ft++)
                *(f32x4*)&lds[h][mt][ft][ln][0] = acc[mt][ft];
            *(f32x4*)&lds[h][mt][4][ln][0] = accs[mt];
        }
    }
    __syncthreads();
    if (jh == 0) {
#pragma unroll
        for (int mt = 0; mt < 2; mt++) {
#pragma unroll
            for (int ft = 0; ft < 4; ft++)
                acc[mt][ft] += *(const f32x4*)&lds[h][mt][ft][ln][0];
            accs[mt] += *(const f32x4*)&lds[h][mt][4][ln][0];
        }
        float bias_v[4];
#pragma unroll
        for (int ft = 0; ft < 4; ft++) bias_v[ft] = bias[h * F_ + ft * 16 + l15];
#pragma unroll
        for (int mt = 0; mt < 2; mt++) {
            f32x4 rinv;
#pragma unroll
            for (int r = 0; r < 4; r++) rinv[r] = 1.0f / accs[mt][r];
#pragma unroll
            for (int ft = 0; ft < 4; ft++)
#pragma unroll
                for (int r = 0; r < 4; r++) {
                    const int i = it0 + mt * 16 + q * 4 + r;
                    const int c = h * F_ + ft * 16 + l15;
                    out[(size_t)(b * N_ + i) * COUT_ + c] = acc[mt][ft][r] * rinv[r] + bias_v[ft];
                }
        }
    }
}

// ---------------------------------------------------------------------------
// Workspace layout (bytes):
//   [0, 128K)    Wtp  bf16 frag-packed [256][256]
//   [128K, +8M)  hp   bf16 frag-packed [B][H][32][4][64][8]
//   +8M: e_src f32 (256K), e_dst f32 (256K), mask u32 (2M). Total ~10.7 MB.
// ---------------------------------------------------------------------------
extern "C" void kernel_launch(void* const* d_in, const int* in_sizes, int n_in,
                              void* d_out, int out_size, void* d_ws, size_t ws_size,
                              hipStream_t stream) {
    const float* x     = (const float*)d_in[0];
    const float* adj   = (const float*)d_in[1];
    const float* W     = (const float*)d_in[2];
    const float* a_src = (const float*)d_in[3];
    const float* a_dst = (const float*)d_in[4];
    const float* bias  = (const float*)d_in[5];
    float* out = (float*)d_out;

    char* ws = (char*)d_ws;
    unsigned short* Wtp = (unsigned short*)ws;
    unsigned short* hp  = (unsigned short*)(ws + 131072);
    float* e_src        = (float*)(ws + 131072 + 8388608);
    float* e_dst        = (float*)(ws + 131072 + 8388608 + 262144);
    unsigned int* mask  = (unsigned int*)(ws + 131072 + 8388608 + 524288);

    prep_kernel<<<256, 256, 0, stream>>>(W, Wtp);
    stage_kernel<<<5120, 256, 0, stream>>>(adj, x, Wtp, a_src, a_dst, mask, hp, e_src, e_dst);
    gat_attn_kernel<<<512, 512, 0, stream>>>(mask, hp, e_src, e_dst, bias, out);
}